// Round 13
// baseline (121.162 us; speedup 1.0000x reference)
//
#include <hip/hip_runtime.h>
#include <math.h>

typedef _Float16 f16;
typedef __fp16 h2 __attribute__((ext_vector_type(2)));
typedef f16 f16x8 __attribute__((ext_vector_type(8)));
typedef float f32x16 __attribute__((ext_vector_type(16)));
typedef unsigned u32;

// ws layout (f16 units):
//  0..49152: w1,w2,w3 A-frags (pi-permuted k): [l][fb][ks][lane][i]
//  W0F 49152 (2048): [fb][lane][i], k=8g+i: k<9 -> w0 row k; k==9 -> b0; else 0
//  W4F 51200 (4096): [ks][lane][i], rows ln<2 = w4 col ln (pi-permuted k), else 0
//  BIAS16 55296 (384): f16 mid-layer bias
// LDS (static): [0,49152) = w1-3 frags; [49152,49536) = bias. 99072 B -> 1 block/CU.
#define LW0 0
#define LW1 16384
#define LW2 32768
#define W0F 49152
#define W4F 51200
#define BIAS16 55296
#define LBIAS 49152
#define LDS_F16 49536

__global__ void zero_f32(float* __restrict__ p, int n) {
    int i = blockIdx.x * blockDim.x + threadIdx.x;
    if (i < n) p[i] = 0.0f;
}

__global__ void prep_weights(const float* __restrict__ w1, const float* __restrict__ w2,
                             const float* __restrict__ w3, const float* __restrict__ w0,
                             const float* __restrict__ b0, const float* __restrict__ b1,
                             const float* __restrict__ b2, const float* __restrict__ b3,
                             const float* __restrict__ w4, f16* __restrict__ ws) {
    int t = blockIdx.x * 256 + threadIdx.x;
    if (t < 49152) {                     // w1,w2,w3 A-frags, pi-permuted k
        int l = t >> 14, rem = t & 16383;
        int fb = rem >> 12, ks = (rem >> 9) & 7, lane = (rem >> 3) & 63, i = rem & 7;
        int g = lane >> 5, ln = lane & 31;
        int F = 32 * (ks >> 1) + (i & 3) + 8 * (2 * (ks & 1) + (i >> 2)) + 4 * g;
        const float* w = (l == 0) ? w1 : (l == 1) ? w2 : w3;
        ws[t] = (f16)w[F * 128 + 32 * fb + ln];
    } else if (t < 51200) {              // w0 A-frags + b0 row at k=9
        int rem = t - 49152;
        int fb = rem >> 9, lane = (rem >> 3) & 63, i = rem & 7;
        int g = lane >> 5, ln = lane & 31;
        int k = 8 * g + i;
        int f = 32 * fb + ln;
        float v = (k < 9) ? w0[k * 128 + f] : (k == 9 ? b0[f] : 0.0f);
        ws[t] = (f16)v;
    } else if (t < 55296) {              // w4 A-frags, pi-permuted k
        int rem = t - 51200;
        int ks = rem >> 9, lane = (rem >> 3) & 63, i = rem & 7;
        int g = lane >> 5, ln = lane & 31;
        int F = 32 * (ks >> 1) + (i & 3) + 8 * (2 * (ks & 1) + (i >> 2)) + 4 * g;
        ws[t] = (ln < 2) ? (f16)w4[F * 2 + ln] : (f16)0;
    } else if (t < 55680) {              // packed f16 mid-layer bias
        int m = t - 55296;
        int i = m & 7, g = (m >> 3) & 1, half = (m >> 4) & 1, fb = (m >> 5) & 3, lm = m >> 7;
        const float* bl = (lm == 0) ? b1 : (lm == 1) ? b2 : b3;
        ws[t] = (f16)bl[32 * fb + (i & 3) + 8 * (2 * half + (i >> 2)) + 4 * g];
    }
}

#define MF(w, b, c) __builtin_amdgcn_mfma_f32_32x32x16_f16(w, b, c, 0, 0, 0)
#define ZACC(acc) { _Pragma("unroll") for (int r_ = 0; r_ < 16; ++r_) acc[r_] = 0.0f; }

#define PACKB(dst, acc, b) {                                                   \
    h2 z2; z2[0] = (__fp16)0; z2[1] = (__fp16)0;                               \
    h2 p0 = __builtin_elementwise_max(__builtin_amdgcn_cvt_pkrtz(acc[8*(b)+0], acc[8*(b)+1]), z2); \
    h2 p1 = __builtin_elementwise_max(__builtin_amdgcn_cvt_pkrtz(acc[8*(b)+2], acc[8*(b)+3]), z2); \
    h2 p2 = __builtin_elementwise_max(__builtin_amdgcn_cvt_pkrtz(acc[8*(b)+4], acc[8*(b)+5]), z2); \
    h2 p3 = __builtin_elementwise_max(__builtin_amdgcn_cvt_pkrtz(acc[8*(b)+6], acc[8*(b)+7]), z2); \
    dst[0]=p0[0]; dst[1]=p0[1]; dst[2]=p1[0]; dst[3]=p1[1];                    \
    dst[4]=p2[0]; dst[5]=p2[1]; dst[6]=p3[0]; dst[7]=p3[1]; }

#define PACKBB(dst, acc, b, bias) {                                            \
    h2 z2; z2[0] = (__fp16)0; z2[1] = (__fp16)0;                               \
    const h2* bp_ = (const h2*)&(bias);                                        \
    h2 p0 = __builtin_elementwise_max(__builtin_amdgcn_cvt_pkrtz(acc[8*(b)+0], acc[8*(b)+1]) + bp_[0], z2); \
    h2 p1 = __builtin_elementwise_max(__builtin_amdgcn_cvt_pkrtz(acc[8*(b)+2], acc[8*(b)+3]) + bp_[1], z2); \
    h2 p2 = __builtin_elementwise_max(__builtin_amdgcn_cvt_pkrtz(acc[8*(b)+4], acc[8*(b)+5]) + bp_[2], z2); \
    h2 p3 = __builtin_elementwise_max(__builtin_amdgcn_cvt_pkrtz(acc[8*(b)+6], acc[8*(b)+7]) + bp_[3], z2); \
    dst[0]=p0[0]; dst[1]=p0[1]; dst[2]=p1[0]; dst[3]=p1[1];                    \
    dst[4]=p2[0]; dst[5]=p2[1]; dst[6]=p3[0]; dst[7]=p3[1]; }

// one weight read feeds BOTH chunks' MFMA streams
#define MIDFB2(LBASE, lm, fb, IA, IB, OA0, OA1, OB0, OB1) {                    \
    f32x16 accA; ZACC(accA); f32x16 accB; ZACC(accB);                          \
    const f16* wb = lds + (LBASE) + (fb) * 4096 + lane * 8;                    \
    f16x8 w;                                                                   \
    w = *(const f16x8*)(wb + 0*512); accA = MF(w, IA##0, accA); accB = MF(w, IB##0, accB); \
    w = *(const f16x8*)(wb + 1*512); accA = MF(w, IA##1, accA); accB = MF(w, IB##1, accB); \
    w = *(const f16x8*)(wb + 2*512); accA = MF(w, IA##2, accA); accB = MF(w, IB##2, accB); \
    w = *(const f16x8*)(wb + 3*512); accA = MF(w, IA##3, accA); accB = MF(w, IB##3, accB); \
    w = *(const f16x8*)(wb + 4*512); accA = MF(w, IA##4, accA); accB = MF(w, IB##4, accB); \
    w = *(const f16x8*)(wb + 5*512); accA = MF(w, IA##5, accA); accB = MF(w, IB##5, accB); \
    w = *(const f16x8*)(wb + 6*512); accA = MF(w, IA##6, accA); accB = MF(w, IB##6, accB); \
    w = *(const f16x8*)(wb + 7*512); accA = MF(w, IA##7, accA); accB = MF(w, IB##7, accB); \
    f16x8 bb0 = lbv[((((lm)*4+(fb))*2+0)*2)+g];                                \
    f16x8 bb1 = lbv[((((lm)*4+(fb))*2+1)*2)+g];                                \
    PACKBB(OA0, accA, 0, bb0); PACKBB(OA1, accA, 1, bb1);                      \
    PACKBB(OB0, accB, 0, bb0); PACKBB(OB1, accB, 1, bb1); }

#define MIDLAYER2(LBASE, lm, IA, IB, OA, OB)                                   \
    MIDFB2(LBASE, lm, 0, IA, IB, OA##0, OA##1, OB##0, OB##1);                  \
    MIDFB2(LBASE, lm, 1, IA, IB, OA##2, OA##3, OB##2, OB##3);                  \
    MIDFB2(LBASE, lm, 2, IA, IB, OA##4, OA##5, OB##4, OB##5);                  \
    MIDFB2(LBASE, lm, 3, IA, IB, OA##6, OA##7, OB##6, OB##7);

#define L0FB2(fb, OA0, OA1, OB0, OB1) {                                        \
    f32x16 accA; ZACC(accA); f32x16 accB; ZACC(accB);                          \
    f16x8 w = w0gv[(fb) * 64 + lane];                                          \
    accA = MF(w, bhA, accA); accA = MF(w, bloA, accA);                         \
    accB = MF(w, bhB, accB); accB = MF(w, bloB, accB);                         \
    PACKB(OA0, accA, 0); PACKB(OA1, accA, 1);                                  \
    PACKB(OB0, accB, 0); PACKB(OB1, accB, 1); }

union F8U { f16x8 v; u32 d[4]; };
static __device__ __forceinline__ u32 pk2(f16 a, f16 b) {
    union { h2 v; u32 u; } c;
    c.v[0] = (__fp16)a; c.v[1] = (__fp16)b;
    return c.u;
}

__launch_bounds__(512, 1)
__global__ void gnn_mfma(const float* __restrict__ pos, const float* __restrict__ vel,
                         const float* __restrict__ a, const float* __restrict__ vnorm,
                         const float* __restrict__ b4,
                         const int* __restrict__ ei, const int* __restrict__ did,
                         const f16* __restrict__ ws, float* __restrict__ out,
                         int nNodes, int nEdges)
{
    __shared__ __align__(16) f16 lds[LDS_F16];

    const int tid = threadIdx.x;
    const int lane = tid & 63;
    const int wid = tid >> 6;
    const int g = lane >> 5;
    const int cl = lane & 31;

    // ---- stage w1-3 frags + packed bias into LDS (one barrier) ----
    {
        const f16x8* wv = (const f16x8*)ws;
        f16x8* lv = (f16x8*)lds;
        #pragma unroll
        for (int it = 0; it < 12; ++it) lv[it * 512 + tid] = wv[it * 512 + tid];
        if (tid < 48) lv[6144 + tid] = wv[6912 + tid];
    }
    __syncthreads();

    const f16x8* w0gv = (const f16x8*)(ws + W0F);
    const f16x8* w4gv = (const f16x8*)(ws + W4F);
    const f16x8* lbv  = (const f16x8*)(lds + LBIAS);

    // ---- gather: 64 edges per wave, one per lane ----
    const int base = blockIdx.x * 512 + wid * 64;
    const int e = base + lane;
    float fx0=0,fx1=0,fx2=0,fx3=0,fx4=0,fx5=0,fx6=0,fx7=0,fx8=0;
    int dsti = 0;
    if (e < nEdges) {
        dsti = ei[e];
        int srci = ei[nEdges + e];
        float2 pd = ((const float2*)pos)[dsti];
        float2 ps = ((const float2*)pos)[srci];
        float2 vd = ((const float2*)vel)[dsti];
        float2 vs = ((const float2*)vel)[srci];
        const float2* embp = (const float2*)(a + (size_t)did[0] * (size_t)nNodes * 2);
        float2 ae = embp[dsti];
        float invn = 1.0f / vnorm[0];
        fx0 = (ps.x - pd.x) / 0.1f;
        fx1 = (ps.y - pd.y) / 0.1f;
        fx2 = sqrtf(fx0 * fx0 + fx1 * fx1);
        fx3 = vd.x * invn; fx4 = vd.y * invn;
        fx5 = vs.x * invn; fx6 = vs.y * invn;
        fx7 = ae.x; fx8 = ae.y;
    }

    // own-edge fragments: X = feats0-7 hi, Xl = lo; y = (feat8, 1.0) hi, (feat8lo, 0) lo
    F8U X, Xl;
    {
        f16 h;
        h=(f16)fx0; X.v[0]=h; Xl.v[0]=(f16)(fx0-(float)h);
        h=(f16)fx1; X.v[1]=h; Xl.v[1]=(f16)(fx1-(float)h);
        h=(f16)fx2; X.v[2]=h; Xl.v[2]=(f16)(fx2-(float)h);
        h=(f16)fx3; X.v[3]=h; Xl.v[3]=(f16)(fx3-(float)h);
        h=(f16)fx4; X.v[4]=h; Xl.v[4]=(f16)(fx4-(float)h);
        h=(f16)fx5; X.v[5]=h; Xl.v[5]=(f16)(fx5-(float)h);
        h=(f16)fx6; X.v[6]=h; Xl.v[6]=(f16)(fx6-(float)h);
        h=(f16)fx7; X.v[7]=h; Xl.v[7]=(f16)(fx7-(float)h);
    }
    f16 h8 = (f16)fx8;
    u32 yh = pk2(h8, (f16)1.0f);                 // k=8 feat + k=9 bias-row 1.0
    u32 yl = pk2((f16)(fx8 - (float)h8), (f16)0);

    // cross-half exchange (all shuffles wave-uniform, outside branches)
    u32 yhA = (u32)__shfl((int)yh, cl);
    u32 ylA = (u32)__shfl((int)yl, cl);
    u32 xb0 = (u32)__shfl((int)X.d[0],  cl + 32);
    u32 xb1 = (u32)__shfl((int)X.d[1],  cl + 32);
    u32 xb2 = (u32)__shfl((int)X.d[2],  cl + 32);
    u32 xb3 = (u32)__shfl((int)X.d[3],  cl + 32);
    u32 xl0 = (u32)__shfl((int)Xl.d[0], cl + 32);
    u32 xl1 = (u32)__shfl((int)Xl.d[1], cl + 32);
    u32 xl2 = (u32)__shfl((int)Xl.d[2], cl + 32);
    u32 xl3 = (u32)__shfl((int)Xl.d[3], cl + 32);
    int dB  = __shfl(dsti, cl + 32);

    F8U uA, uAl, uB, uBl;
    uA.d[0]  = g ? yhA : X.d[0];  uA.d[1]  = g ? 0u : X.d[1];
    uA.d[2]  = g ? 0u  : X.d[2];  uA.d[3]  = g ? 0u : X.d[3];
    uAl.d[0] = g ? ylA : Xl.d[0]; uAl.d[1] = g ? 0u : Xl.d[1];
    uAl.d[2] = g ? 0u  : Xl.d[2]; uAl.d[3] = g ? 0u : Xl.d[3];
    uB.d[0]  = g ? yh  : xb0;     uB.d[1]  = g ? 0u : xb1;
    uB.d[2]  = g ? 0u  : xb2;     uB.d[3]  = g ? 0u : xb3;
    uBl.d[0] = g ? yl  : xl0;     uBl.d[1] = g ? 0u : xl1;
    uBl.d[2] = g ? 0u  : xl2;     uBl.d[3] = g ? 0u : xl3;
    f16x8 bhA = uA.v, bloA = uAl.v, bhB = uB.v, bloB = uBl.v;

    // ---- MLP: 2 chunks per wave, fully in registers ----
    f16x8 PaA0,PaA1,PaA2,PaA3,PaA4,PaA5,PaA6,PaA7;
    f16x8 PaB0,PaB1,PaB2,PaB3,PaB4,PaB5,PaB6,PaB7;
    f16x8 PbA0,PbA1,PbA2,PbA3,PbA4,PbA5,PbA6,PbA7;
    f16x8 PbB0,PbB1,PbB2,PbB3,PbB4,PbB5,PbB6,PbB7;

    L0FB2(0, PaA0, PaA1, PaB0, PaB1);
    L0FB2(1, PaA2, PaA3, PaB2, PaB3);
    L0FB2(2, PaA4, PaA5, PaB4, PaB5);
    L0FB2(3, PaA6, PaA7, PaB6, PaB7);

    MIDLAYER2(LW0, 0, PaA, PaB, PbA, PbB)
    MIDLAYER2(LW1, 1, PbA, PbB, PaA, PaB)
    MIDLAYER2(LW2, 2, PaA, PaB, PbA, PbB)

    // ---- final layer 128 -> 2, shared w4 reads, atomic segment-sum ----
    {
        const float b40 = b4[0], b41 = b4[1];
        f32x16 accA; ZACC(accA); f32x16 accB; ZACC(accB);
        if (g == 0) { accA[0] = b40; accA[1] = b41; accB[0] = b40; accB[1] = b41; }
        f16x8 w;
        w = w4gv[0*64 + lane]; accA = MF(w, PbA0, accA); accB = MF(w, PbB0, accB);
        w = w4gv[1*64 + lane]; accA = MF(w, PbA1, accA); accB = MF(w, PbB1, accB);
        w = w4gv[2*64 + lane]; accA = MF(w, PbA2, accA); accB = MF(w, PbB2, accB);
        w = w4gv[3*64 + lane]; accA = MF(w, PbA3, accA); accB = MF(w, PbB3, accB);
        w = w4gv[4*64 + lane]; accA = MF(w, PbA4, accA); accB = MF(w, PbB4, accB);
        w = w4gv[5*64 + lane]; accA = MF(w, PbA5, accA); accB = MF(w, PbB5, accB);
        w = w4gv[6*64 + lane]; accA = MF(w, PbA6, accA); accB = MF(w, PbB6, accB);
        w = w4gv[7*64 + lane]; accA = MF(w, PbA7, accA); accB = MF(w, PbB7, accB);
        if (g == 0) {
            if (base + cl < nEdges) {
                atomicAdd(&out[2 * dsti],     accA[0]);
                atomicAdd(&out[2 * dsti + 1], accA[1]);
            }
            if (base + 32 + cl < nEdges) {
                atomicAdd(&out[2 * dB],       accB[0]);
                atomicAdd(&out[2 * dB + 1],   accB[1]);
            }
        }
    }
}

extern "C" void kernel_launch(void* const* d_in, const int* in_sizes, int n_in,
                              void* d_out, int out_size, void* d_ws, size_t ws_size,
                              hipStream_t stream) {
    const float* pos   = (const float*)d_in[0];
    const float* vel   = (const float*)d_in[1];
    const float* a     = (const float*)d_in[2];
    const float* vnorm = (const float*)d_in[3];
    const float* w0    = (const float*)d_in[4];
    const float* b0    = (const float*)d_in[5];
    const float* w1    = (const float*)d_in[6];
    const float* b1    = (const float*)d_in[7];
    const float* w2    = (const float*)d_in[8];
    const float* b2    = (const float*)d_in[9];
    const float* w3    = (const float*)d_in[10];
    const float* b3    = (const float*)d_in[11];
    const float* w4    = (const float*)d_in[12];
    const float* b4    = (const float*)d_in[13];
    const int*   ei    = (const int*)d_in[14];
    const int*   did   = (const int*)d_in[15];
    float* out = (float*)d_out;
    f16* ws = (f16*)d_ws;

    int nEdges = in_sizes[14] / 2;   // 800000
    int nNodes = in_sizes[0] / 2;    // 50000

    hipLaunchKernelGGL(zero_f32, dim3((out_size + 255) / 256), dim3(256), 0, stream,
                       out, out_size);
    hipLaunchKernelGGL(prep_weights, dim3(218), dim3(256), 0, stream,
                       w1, w2, w3, w0, b0, b1, b2, b3, w4, ws);
    int grid = (nEdges + 511) / 512;              // 1563 blocks of 8 waves x 64 edges
    hipLaunchKernelGGL(gnn_mfma, dim3(grid), dim3(512), 0, stream,
                       pos, vel, a, vnorm, b4, ei, did, ws, out,
                       nNodes, nEdges);
}